// Round 1
// baseline (464.744 us; speedup 1.0000x reference)
//
#include <hip/hip_runtime.h>

// Flash attention for B=2,H=8,N=4096,d=64 fp32 (QKV packed [3,16,4096,64]).
// bf16 MFMA with split-precision (hi+lo) QK^T for accuracy; plain bf16 PV.
// Block = 256 threads (4 waves), each wave owns 16 Q rows; Q-tile 64 rows,
// KV-tile 64 cols; 16 bh * 64 qtiles = 1024 blocks = 4 blocks/CU (LDS 36KB).

typedef short bf16x8 __attribute__((ext_vector_type(8)));
typedef float f32x4 __attribute__((ext_vector_type(4)));

#define NHEADS 16
#define SEQ 4096
#define HDIM 64
#define BR 64
#define BC 64
#define KP 72   // LDS pitch: 144B rows -> 16B aligned, 2-way bank access (free)

__device__ __forceinline__ unsigned short f2bf(float f) {
  unsigned int u = __float_as_uint(f);
  u += 0x7fffu + ((u >> 16) & 1u);   // RNE bf16 (inputs are finite normals)
  return (unsigned short)(u >> 16);
}
__device__ __forceinline__ float bf2f(unsigned short h) {
  return __uint_as_float(((unsigned int)h) << 16);
}

__global__ __launch_bounds__(256, 4) void flash_attn(const float* __restrict__ QKV,
                                                     float* __restrict__ Out) {
  const size_t headElems = (size_t)SEQ * HDIM;          // 262144
  const size_t tensElems = (size_t)NHEADS * headElems;  // 4194304
  // bh = blockIdx & 15: same-bh blocks spaced 16 apart -> same XCD (i%8
  // round-robin heuristic) -> per-XCD L2 holds K+V of only 2 heads (4 MB).
  const int bh = blockIdx.x & 15;
  const int qt = blockIdx.x >> 4;

  const float* Q = QKV + (size_t)bh * headElems;
  const float* K = QKV + tensElems + (size_t)bh * headElems;
  const float* V = QKV + 2 * tensElems + (size_t)bh * headElems;
  float* O = Out + (size_t)bh * headElems;

  const int tid = threadIdx.x;
  const int wave = tid >> 6;
  const int lane = tid & 63;
  const int g = lane >> 4;     // quad group
  const int l16 = lane & 15;

  __shared__ __align__(16) unsigned short Kh[BC * KP];
  __shared__ __align__(16) unsigned short Kl[BC * KP];
  __shared__ __align__(16) unsigned short Vt[HDIM * KP];   // transposed V
  __shared__ __align__(16) unsigned short Ps[4][16 * KP];  // per-wave P buffer

  // ---- Q fragments (hi/lo split), loaded once ----
  // A-layout: A[m=lane&15][k=(lane>>4)*8 + j]
  const int qrow = qt * BR + wave * 16 + l16;
  bf16x8 qh[2], ql[2];
  #pragma unroll
  for (int c = 0; c < 2; ++c) {
    const float* qp = Q + (size_t)qrow * HDIM + c * 32 + g * 8;
    union { bf16x8 v; unsigned short s[8]; } uh, ul;
    #pragma unroll
    for (int j = 0; j < 8; ++j) {
      float x = qp[j];
      unsigned short hi = f2bf(x);
      uh.s[j] = hi;
      ul.s[j] = f2bf(x - bf2f(hi));
    }
    qh[c] = uh.v;
    ql[c] = ul.v;
  }

  f32x4 acc[4];
  #pragma unroll
  for (int nt = 0; nt < 4; ++nt)
    #pragma unroll
    for (int i = 0; i < 4; ++i) acc[nt][i] = 0.f;
  float mrow[4], lrow[4];
  #pragma unroll
  for (int i = 0; i < 4; ++i) { mrow[i] = -1e30f; lrow[i] = 0.f; }

  for (int kt = 0; kt < SEQ / BC; ++kt) {
    __syncthreads();  // previous iter's LDS reads done before overwrite
    // ---- stage K (hi+lo) and V^T tiles ----
    #pragma unroll
    for (int it = 0; it < 4; ++it) {
      int idx = tid + it * 256;
      int row = idx >> 4;           // 0..63
      int c4 = (idx & 15) << 2;     // 0..60
      float4 kv = *(const float4*)(K + (size_t)(kt * BC + row) * HDIM + c4);
      ushort4 khv, klv;
      khv.x = f2bf(kv.x); klv.x = f2bf(kv.x - bf2f(khv.x));
      khv.y = f2bf(kv.y); klv.y = f2bf(kv.y - bf2f(khv.y));
      khv.z = f2bf(kv.z); klv.z = f2bf(kv.z - bf2f(khv.z));
      khv.w = f2bf(kv.w); klv.w = f2bf(kv.w - bf2f(khv.w));
      *(ushort4*)&Kh[row * KP + c4] = khv;
      *(ushort4*)&Kl[row * KP + c4] = klv;
      float4 vv = *(const float4*)(V + (size_t)(kt * BC + row) * HDIM + c4);
      Vt[(c4 + 0) * KP + row] = f2bf(vv.x);
      Vt[(c4 + 1) * KP + row] = f2bf(vv.y);
      Vt[(c4 + 2) * KP + row] = f2bf(vv.z);
      Vt[(c4 + 3) * KP + row] = f2bf(vv.w);
    }
    __syncthreads();

    // ---- S = Q K^T (split precision) ----
    // B-layout for A.B^T: lane reads K[lane&15 + 16*jt][(lane>>4)*8 + 32c + j]
    f32x4 s[4];
    #pragma unroll
    for (int jt = 0; jt < 4; ++jt) {
      const int krow = (jt * 16 + l16) * KP + g * 8;
      bf16x8 kh0 = *(const bf16x8*)&Kh[krow];
      bf16x8 kh1 = *(const bf16x8*)&Kh[krow + 32];
      bf16x8 kl0 = *(const bf16x8*)&Kl[krow];
      bf16x8 kl1 = *(const bf16x8*)&Kl[krow + 32];
      f32x4 z;
      z[0] = z[1] = z[2] = z[3] = 0.f;
      z = __builtin_amdgcn_mfma_f32_16x16x32_bf16(qh[0], kh0, z, 0, 0, 0);
      z = __builtin_amdgcn_mfma_f32_16x16x32_bf16(qh[1], kh1, z, 0, 0, 0);
      z = __builtin_amdgcn_mfma_f32_16x16x32_bf16(ql[0], kh0, z, 0, 0, 0);
      z = __builtin_amdgcn_mfma_f32_16x16x32_bf16(ql[1], kh1, z, 0, 0, 0);
      z = __builtin_amdgcn_mfma_f32_16x16x32_bf16(qh[0], kl0, z, 0, 0, 0);
      z = __builtin_amdgcn_mfma_f32_16x16x32_bf16(qh[1], kl1, z, 0, 0, 0);
      s[jt] = z;
    }

    // ---- online softmax (C/D layout: row = g*4+ri, col = jt*16 + l16) ----
    float alpha[4];
    #pragma unroll
    for (int ri = 0; ri < 4; ++ri) {
      float v = fmaxf(fmaxf(s[0][ri], s[1][ri]), fmaxf(s[2][ri], s[3][ri]));
      v = fmaxf(v, __shfl_xor(v, 1));
      v = fmaxf(v, __shfl_xor(v, 2));
      v = fmaxf(v, __shfl_xor(v, 4));
      v = fmaxf(v, __shfl_xor(v, 8));
      float mnew = fmaxf(mrow[ri], v);
      alpha[ri] = __expf(mrow[ri] - mnew);
      mrow[ri] = mnew;
      float ps = 0.f;
      #pragma unroll
      for (int jt = 0; jt < 4; ++jt) {
        float p = __expf(s[jt][ri] - mnew);
        ps += p;
        Ps[wave][(g * 4 + ri) * KP + jt * 16 + l16] = f2bf(p);
      }
      ps += __shfl_xor(ps, 1);
      ps += __shfl_xor(ps, 2);
      ps += __shfl_xor(ps, 4);
      ps += __shfl_xor(ps, 8);
      lrow[ri] = lrow[ri] * alpha[ri] + ps;
    }
    #pragma unroll
    for (int nt = 0; nt < 4; ++nt)
      #pragma unroll
      for (int ri = 0; ri < 4; ++ri) acc[nt][ri] *= alpha[ri];

    __syncthreads();  // P writes (C-layout) -> P reads (A-layout)

    // ---- O += P V ----
    bf16x8 pa0 = *(const bf16x8*)&Ps[wave][l16 * KP + g * 8];
    bf16x8 pa1 = *(const bf16x8*)&Ps[wave][l16 * KP + 32 + g * 8];
    #pragma unroll
    for (int nt = 0; nt < 4; ++nt) {
      const int vrow = (nt * 16 + l16) * KP + g * 8;
      bf16x8 vb0 = *(const bf16x8*)&Vt[vrow];
      bf16x8 vb1 = *(const bf16x8*)&Vt[vrow + 32];
      acc[nt] = __builtin_amdgcn_mfma_f32_16x16x32_bf16(pa0, vb0, acc[nt], 0, 0, 0);
      acc[nt] = __builtin_amdgcn_mfma_f32_16x16x32_bf16(pa1, vb1, acc[nt], 0, 0, 0);
    }
  }

  // ---- epilogue ----
  #pragma unroll
  for (int ri = 0; ri < 4; ++ri) {
    float inv = 1.0f / lrow[ri];
    int grow = qt * BR + wave * 16 + g * 4 + ri;
    #pragma unroll
    for (int nt = 0; nt < 4; ++nt) {
      O[(size_t)grow * HDIM + nt * 16 + l16] = acc[nt][ri] * inv;
    }
  }
}

extern "C" void kernel_launch(void* const* d_in, const int* in_sizes, int n_in,
                              void* d_out, int out_size, void* d_ws, size_t ws_size,
                              hipStream_t stream) {
  const float* QKV = (const float*)d_in[0];
  float* Out = (float*)d_out;
  dim3 grid(NHEADS * (SEQ / BR));  // 1024
  dim3 block(256);
  hipLaunchKernelGGL(flash_attn, grid, block, 0, stream, QKV, Out);
}

// Round 2
// 299.412 us; speedup vs baseline: 1.5522x; 1.5522x over previous
//
#include <hip/hip_runtime.h>

// Flash attention B=2,H=8,N=4096,d=64 fp32 in/out (QKV packed [3,16,4096,64]).
// Round 2: fp16 MFMA path. Prepass converts K->fp16 and V->fp16-transposed
// into d_ws so the main loop does zero conversion work; single-MFMA QK
// (fp16 accuracy beats bf16 hi/lo on the PV side); exp2-based softmax with
// log2(e) folded into Q; conflict-free b128 LDS staging.

typedef _Float16 f16x8 __attribute__((ext_vector_type(8)));
typedef _Float16 f16x4 __attribute__((ext_vector_type(4)));
typedef float f32x4 __attribute__((ext_vector_type(4)));

#define NHEADS 16
#define SEQ 4096
#define HDIM 64
#define BR 64
#define BC 64
#define KP 72   // LDS pitch (halves): 144B rows -> b128 access conflict-free

__device__ __forceinline__ float fast_exp2(float x) {
#if __has_builtin(__builtin_amdgcn_exp2f)
  return __builtin_amdgcn_exp2f(x);
#else
  return exp2f(x);
#endif
}

// ---- prepass 1: K fp32 -> fp16, layout preserved [16][4096][64] ----
__global__ __launch_bounds__(256) void conv_k(const float* __restrict__ K,
                                              _Float16* __restrict__ K16) {
  size_t i = ((size_t)blockIdx.x * 256 + threadIdx.x) * 8;
  float4 a = *(const float4*)(K + i);
  float4 b = *(const float4*)(K + i + 4);
  f16x8 h;
  h[0] = (_Float16)a.x; h[1] = (_Float16)a.y; h[2] = (_Float16)a.z; h[3] = (_Float16)a.w;
  h[4] = (_Float16)b.x; h[5] = (_Float16)b.y; h[6] = (_Float16)b.z; h[7] = (_Float16)b.w;
  *(f16x8*)(K16 + i) = h;
}

// ---- prepass 2: V fp32 [16][4096][64] -> fp16 transposed [16][64][4096] ----
__global__ __launch_bounds__(256) void conv_vt(const float* __restrict__ V,
                                               _Float16* __restrict__ Vt) {
  const int bh = blockIdx.x >> 6;
  const int nt = blockIdx.x & 63;
  __shared__ __align__(16) _Float16 T[64 * KP];
  const float* Vh = V + (size_t)bh * SEQ * HDIM + (size_t)nt * 64 * HDIM;
  const int t = threadIdx.x;
  #pragma unroll
  for (int p = 0; p < 4; ++p) {
    int idx = t + p * 256;
    int row = idx >> 4, c4 = (idx & 15) << 2;
    float4 v = *(const float4*)(Vh + row * HDIM + c4);
    f16x4 h;
    h[0] = (_Float16)v.x; h[1] = (_Float16)v.y; h[2] = (_Float16)v.z; h[3] = (_Float16)v.w;
    *(f16x4*)&T[row * KP + c4] = h;
  }
  __syncthreads();
  const int d = t & 63, w = t >> 6;   // wave w handles n-chunk w*16..w*16+15
  f16x8 o0, o1;
  #pragma unroll
  for (int j = 0; j < 8; ++j) o0[j] = T[(w * 16 + j) * KP + d];
  #pragma unroll
  for (int j = 0; j < 8; ++j) o1[j] = T[(w * 16 + 8 + j) * KP + d];
  _Float16* out = Vt + (size_t)bh * HDIM * SEQ + (size_t)d * SEQ + nt * 64 + w * 16;
  *(f16x8*)out = o0;
  *(f16x8*)(out + 8) = o1;
}

// ---- main flash-attention kernel ----
template <bool PRE>
__global__ __launch_bounds__(256, 4) void flash_attn(const float* __restrict__ QKV,
                                                     const _Float16* __restrict__ K16,
                                                     const _Float16* __restrict__ Vt16,
                                                     float* __restrict__ Out) {
  const size_t headElems = (size_t)SEQ * HDIM;          // 262144
  const size_t tensElems = (size_t)NHEADS * headElems;  // 4194304
  const int bh = blockIdx.x & 15;   // same-bh blocks 16 apart -> same XCD
  const int qt = blockIdx.x >> 4;

  const float* Q = QKV + (size_t)bh * headElems;
  float* O = Out + (size_t)bh * headElems;

  const int tid = threadIdx.x;
  const int wave = tid >> 6;
  const int lane = tid & 63;
  const int g = lane >> 4;
  const int l16 = lane & 15;

  __shared__ __align__(16) _Float16 Ks[BC * KP];
  __shared__ __align__(16) _Float16 Vs[HDIM * KP];
  __shared__ __align__(16) _Float16 Ps[4][16 * KP];

  // Q fragment, pre-scaled by log2(e) so softmax uses exp2 directly.
  const float LOG2E = 1.4426950408889634f;
  const int qrow = qt * BR + wave * 16 + l16;
  f16x8 qf[2];
  #pragma unroll
  for (int c = 0; c < 2; ++c) {
    const float* qp = Q + (size_t)qrow * HDIM + c * 32 + g * 8;
    f16x8 h;
    #pragma unroll
    for (int j = 0; j < 8; ++j) h[j] = (_Float16)(qp[j] * LOG2E);
    qf[c] = h;
  }

  f32x4 acc[4];
  #pragma unroll
  for (int nt = 0; nt < 4; ++nt)
    #pragma unroll
    for (int i = 0; i < 4; ++i) acc[nt][i] = 0.f;
  float mrow[4], lrow[4];
  #pragma unroll
  for (int i = 0; i < 4; ++i) { mrow[i] = -1e30f; lrow[i] = 0.f; }

  for (int kt = 0; kt < SEQ / BC; ++kt) {
    __syncthreads();  // prior iter's Ks/Vs reads done before overwrite
    if (PRE) {
      const _Float16* Kg = K16 + (size_t)bh * headElems + (size_t)kt * BC * HDIM;
      const _Float16* Vg = Vt16 + (size_t)bh * headElems + (size_t)kt * BC;
      #pragma unroll
      for (int p = 0; p < 2; ++p) {
        int idx = tid + p * 256;
        int r = idx >> 3, c8 = (idx & 7) << 3;
        *(f16x8*)&Ks[r * KP + c8] = *(const f16x8*)(Kg + r * HDIM + c8);
        *(f16x8*)&Vs[r * KP + c8] = *(const f16x8*)(Vg + (size_t)r * SEQ + c8);
      }
    } else {
      const float* K = QKV + tensElems + (size_t)bh * headElems;
      const float* V = QKV + 2 * tensElems + (size_t)bh * headElems;
      #pragma unroll
      for (int p = 0; p < 4; ++p) {
        int idx = tid + p * 256;
        int r = idx >> 4, c4 = (idx & 15) << 2;
        float4 kv = *(const float4*)(K + (size_t)(kt * BC + r) * HDIM + c4);
        f16x4 kh;
        kh[0] = (_Float16)kv.x; kh[1] = (_Float16)kv.y;
        kh[2] = (_Float16)kv.z; kh[3] = (_Float16)kv.w;
        *(f16x4*)&Ks[r * KP + c4] = kh;
        float4 vv = *(const float4*)(V + (size_t)(kt * BC + r) * HDIM + c4);
        Vs[(c4 + 0) * KP + r] = (_Float16)vv.x;
        Vs[(c4 + 1) * KP + r] = (_Float16)vv.y;
        Vs[(c4 + 2) * KP + r] = (_Float16)vv.z;
        Vs[(c4 + 3) * KP + r] = (_Float16)vv.w;
      }
    }
    __syncthreads();

    // ---- S' = (Q*log2e) K^T ----
    f32x4 s[4];
    #pragma unroll
    for (int jt = 0; jt < 4; ++jt) {
      const int krow = (jt * 16 + l16) * KP + g * 8;
      f16x8 k0 = *(const f16x8*)&Ks[krow];
      f16x8 k1 = *(const f16x8*)&Ks[krow + 32];
      f32x4 z;
      z[0] = z[1] = z[2] = z[3] = 0.f;
      z = __builtin_amdgcn_mfma_f32_16x16x32_f16(qf[0], k0, z, 0, 0, 0);
      z = __builtin_amdgcn_mfma_f32_16x16x32_f16(qf[1], k1, z, 0, 0, 0);
      s[jt] = z;
    }

    // ---- online softmax (C/D layout: row = g*4+ri, col = jt*16+l16) ----
    float alpha[4];
    #pragma unroll
    for (int ri = 0; ri < 4; ++ri) {
      float v = fmaxf(fmaxf(s[0][ri], s[1][ri]), fmaxf(s[2][ri], s[3][ri]));
      v = fmaxf(v, __shfl_xor(v, 1));
      v = fmaxf(v, __shfl_xor(v, 2));
      v = fmaxf(v, __shfl_xor(v, 4));
      v = fmaxf(v, __shfl_xor(v, 8));
      float mnew = fmaxf(mrow[ri], v);
      alpha[ri] = fast_exp2(mrow[ri] - mnew);
      mrow[ri] = mnew;
      float ps = 0.f;
      #pragma unroll
      for (int jt = 0; jt < 4; ++jt) {
        float p = fast_exp2(s[jt][ri] - mnew);
        ps += p;
        Ps[wave][(g * 4 + ri) * KP + jt * 16 + l16] = (_Float16)p;
      }
      ps += __shfl_xor(ps, 1);
      ps += __shfl_xor(ps, 2);
      ps += __shfl_xor(ps, 4);
      ps += __shfl_xor(ps, 8);
      lrow[ri] = lrow[ri] * alpha[ri] + ps;
    }
    #pragma unroll
    for (int nt = 0; nt < 4; ++nt)
      #pragma unroll
      for (int ri = 0; ri < 4; ++ri) acc[nt][ri] *= alpha[ri];

    // No barrier: Ps is per-wave; a wave's DS ops complete in order.

    // ---- O += P V ----
    f16x8 pa0 = *(const f16x8*)&Ps[wave][l16 * KP + g * 8];
    f16x8 pa1 = *(const f16x8*)&Ps[wave][l16 * KP + 32 + g * 8];
    #pragma unroll
    for (int nt = 0; nt < 4; ++nt) {
      const int vrow = (nt * 16 + l16) * KP + g * 8;
      f16x8 vb0 = *(const f16x8*)&Vs[vrow];
      f16x8 vb1 = *(const f16x8*)&Vs[vrow + 32];
      acc[nt] = __builtin_amdgcn_mfma_f32_16x16x32_f16(pa0, vb0, acc[nt], 0, 0, 0);
      acc[nt] = __builtin_amdgcn_mfma_f32_16x16x32_f16(pa1, vb1, acc[nt], 0, 0, 0);
    }
  }

  // ---- epilogue ----
  #pragma unroll
  for (int ri = 0; ri < 4; ++ri) {
    float inv = 1.0f / lrow[ri];
    int grow = qt * BR + wave * 16 + g * 4 + ri;
    #pragma unroll
    for (int nt = 0; nt < 4; ++nt) {
      O[(size_t)grow * HDIM + nt * 16 + l16] = acc[nt][ri] * inv;
    }
  }
}

extern "C" void kernel_launch(void* const* d_in, const int* in_sizes, int n_in,
                              void* d_out, int out_size, void* d_ws, size_t ws_size,
                              hipStream_t stream) {
  const float* QKV = (const float*)d_in[0];
  float* Out = (float*)d_out;
  const size_t tensElems = (size_t)NHEADS * SEQ * HDIM;  // 4194304
  const size_t needBytes = 2 * tensElems * sizeof(_Float16);  // 16.78 MB

  dim3 block(256);
  dim3 grid(NHEADS * (SEQ / BR));  // 1024

  if (ws_size >= needBytes) {
    _Float16* K16 = (_Float16*)d_ws;
    _Float16* Vt16 = K16 + tensElems;
    const float* K = QKV + tensElems;
    const float* V = QKV + 2 * tensElems;
    hipLaunchKernelGGL(conv_k, dim3(tensElems / (256 * 8)), block, 0, stream, K, K16);
    hipLaunchKernelGGL(conv_vt, dim3(NHEADS * (SEQ / 64)), block, 0, stream, V, Vt16);
    hipLaunchKernelGGL((flash_attn<true>), grid, block, 0, stream, QKV, K16, Vt16, Out);
  } else {
    hipLaunchKernelGGL((flash_attn<false>), grid, block, 0, stream, QKV,
                       (const _Float16*)nullptr, (const _Float16*)nullptr, Out);
  }
}

// Round 4
// 199.895 us; speedup vs baseline: 2.3249x; 1.4978x over previous
//
#include <hip/hip_runtime.h>

// Flash attention B=2,H=8,N=4096,d=64 fp32 in/out (QKV packed [3,16,4096,64]).
// Round 4 = Round 3 + compile fix: __builtin_amdgcn_cvt_pkrtz returns a
// __fp16 ext-vector, incompatible with _Float16 vectors -> bit_cast wrapper.
// Design: S^T orientation (A=K, B=Q) puts P k-major per lane -> cheap softmax
// (per-lane max + 2 shuffles, deferred row-sum) and 4xb64 P stores. 32 Q rows
// per wave (BR=128) doubles K/V fragment reuse per LDS read. Register-
// prefetched staging; V^T fp16 prepass only (K converts inline).

typedef _Float16 f16x8 __attribute__((ext_vector_type(8)));
typedef _Float16 f16x4 __attribute__((ext_vector_type(4)));
typedef _Float16 f16x2 __attribute__((ext_vector_type(2)));
typedef float f32x4 __attribute__((ext_vector_type(4)));

#define NHEADS 16
#define SEQ 4096
#define HDIM 64
#define BR 128   // Q rows per block (4 waves x 32)
#define BC 64    // KV cols per iteration
#define KP 72    // LDS pitch (halves) for Ks/Vs: 144B rows, 16B-aligned
#define PP 72    // LDS pitch (halves) for Ps

__device__ __forceinline__ float fast_exp2(float x) {
#if __has_builtin(__builtin_amdgcn_exp2f)
  return __builtin_amdgcn_exp2f(x);
#else
  return exp2f(x);
#endif
}

// v_cvt_pkrtz_f16_f32 packs two f32 -> two f16 (RTZ). Builtin returns a
// 2 x __fp16 vector; bit_cast to our 2 x _Float16 type.
__device__ __forceinline__ f16x2 pkrtz(float a, float b) {
  return __builtin_bit_cast(f16x2, __builtin_amdgcn_cvt_pkrtz(a, b));
}

// ---- prepass: V fp32 [16][4096][64] -> fp16 transposed [16][64][4096] ----
__global__ __launch_bounds__(256) void conv_vt(const float* __restrict__ V,
                                               _Float16* __restrict__ Vt) {
  const int bh = blockIdx.x >> 6;
  const int nt = blockIdx.x & 63;
  __shared__ __align__(16) _Float16 T[64 * KP];
  const float* Vh = V + (size_t)bh * SEQ * HDIM + (size_t)nt * 64 * HDIM;
  const int t = threadIdx.x;
  #pragma unroll
  for (int p = 0; p < 4; ++p) {
    int idx = t + p * 256;
    int row = idx >> 4, c4 = (idx & 15) << 2;
    float4 v = *(const float4*)(Vh + row * HDIM + c4);
    union { f16x4 v4; f16x2 h2[2]; } h;
    h.h2[0] = pkrtz(v.x, v.y);
    h.h2[1] = pkrtz(v.z, v.w);
    *(f16x4*)&T[row * KP + c4] = h.v4;
  }
  __syncthreads();
  const int d = t & 63, w = t >> 6;
  f16x8 o0, o1;
  #pragma unroll
  for (int j = 0; j < 8; ++j) o0[j] = T[(w * 16 + j) * KP + d];
  #pragma unroll
  for (int j = 0; j < 8; ++j) o1[j] = T[(w * 16 + 8 + j) * KP + d];
  _Float16* out = Vt + (size_t)bh * HDIM * SEQ + (size_t)d * SEQ + nt * 64 + w * 16;
  *(f16x8*)out = o0;
  *(f16x8*)(out + 8) = o1;
}

// ---- main kernel ----
template <bool PRE>
__global__ __launch_bounds__(256, 2) void flash_attn(const float* __restrict__ QKV,
                                                     const _Float16* __restrict__ Vt16,
                                                     float* __restrict__ Out) {
  const size_t headElems = (size_t)SEQ * HDIM;
  const size_t tensElems = (size_t)NHEADS * headElems;
  const int bh = blockIdx.x & 15;   // same-bh blocks 16 apart -> same XCD
  const int qt = blockIdx.x >> 4;   // 0..31

  const float* Q = QKV + (size_t)bh * headElems;
  const float* Kf = QKV + tensElems + (size_t)bh * headElems;
  const float* Vf = QKV + 2 * tensElems + (size_t)bh * headElems;
  const _Float16* Vg16 = Vt16 + (size_t)bh * headElems;  // [d][n]
  float* O = Out + (size_t)bh * headElems;

  const int tid = threadIdx.x;
  const int wave = tid >> 6;
  const int lane = tid & 63;
  const int g = lane >> 4;
  const int l16 = lane & 15;

  __shared__ __align__(16) _Float16 Ks[BC * KP];      // [kv][d]
  __shared__ __align__(16) _Float16 Vs[HDIM * KP];    // [d][kv]
  __shared__ __align__(16) _Float16 Ps[4][2][16 * PP];// [wave][h][q(l16)][kv]

  // ---- Q fragments (B operand of S^T): lane l16 = Q row, k = g*8+j ----
  const float LOG2E = 1.4426950408889634f;
  const int qbase = qt * BR + wave * 32;
  f16x8 qf[2][2];
  #pragma unroll
  for (int h = 0; h < 2; ++h) {
    const float* qp = Q + (size_t)(qbase + h * 16 + l16) * HDIM + g * 8;
    #pragma unroll
    for (int c = 0; c < 2; ++c) {
      float4 a = *(const float4*)(qp + c * 32);
      float4 b = *(const float4*)(qp + c * 32 + 4);
      union { f16x8 v; f16x2 h2[4]; } u;
      u.h2[0] = pkrtz(a.x * LOG2E, a.y * LOG2E);
      u.h2[1] = pkrtz(a.z * LOG2E, a.w * LOG2E);
      u.h2[2] = pkrtz(b.x * LOG2E, b.y * LOG2E);
      u.h2[3] = pkrtz(b.z * LOG2E, b.w * LOG2E);
      qf[h][c] = u.v;
    }
  }

  // staging coords: thread covers K row sr, cols sc..sc+15 (same for V^T)
  const int sr = tid >> 2;
  const int sc = (tid & 3) << 4;

  float4 kpre[4];
  f16x8 vpre[2];

  auto prefetch = [&](int kt) {
    if constexpr (PRE) {
      const float* kg = Kf + (size_t)(kt * BC + sr) * HDIM + sc;
      kpre[0] = *(const float4*)(kg);
      kpre[1] = *(const float4*)(kg + 4);
      kpre[2] = *(const float4*)(kg + 8);
      kpre[3] = *(const float4*)(kg + 12);
      const _Float16* vg = Vg16 + (size_t)sr * SEQ + kt * BC + sc;
      vpre[0] = *(const f16x8*)(vg);
      vpre[1] = *(const f16x8*)(vg + 8);
    }
  };
  auto commit = [&](int kt) {
    if constexpr (PRE) {
      union { f16x8 v; f16x2 h2[4]; } ka, kb;
      ka.h2[0] = pkrtz(kpre[0].x, kpre[0].y);
      ka.h2[1] = pkrtz(kpre[0].z, kpre[0].w);
      ka.h2[2] = pkrtz(kpre[1].x, kpre[1].y);
      ka.h2[3] = pkrtz(kpre[1].z, kpre[1].w);
      kb.h2[0] = pkrtz(kpre[2].x, kpre[2].y);
      kb.h2[1] = pkrtz(kpre[2].z, kpre[2].w);
      kb.h2[2] = pkrtz(kpre[3].x, kpre[3].y);
      kb.h2[3] = pkrtz(kpre[3].z, kpre[3].w);
      *(f16x8*)&Ks[sr * KP + sc] = ka.v;
      *(f16x8*)&Ks[sr * KP + sc + 8] = kb.v;
      *(f16x8*)&Vs[sr * KP + sc] = vpre[0];
      *(f16x8*)&Vs[sr * KP + sc + 8] = vpre[1];
    } else {
      const float* kg = Kf + (size_t)(kt * BC + sr) * HDIM + sc;
      float4 a = *(const float4*)(kg), b = *(const float4*)(kg + 4);
      float4 c = *(const float4*)(kg + 8), d = *(const float4*)(kg + 12);
      union { f16x8 v; f16x2 h2[4]; } ka, kb;
      ka.h2[0] = pkrtz(a.x, a.y);
      ka.h2[1] = pkrtz(a.z, a.w);
      ka.h2[2] = pkrtz(b.x, b.y);
      ka.h2[3] = pkrtz(b.z, b.w);
      kb.h2[0] = pkrtz(c.x, c.y);
      kb.h2[1] = pkrtz(c.z, c.w);
      kb.h2[2] = pkrtz(d.x, d.y);
      kb.h2[3] = pkrtz(d.z, d.w);
      *(f16x8*)&Ks[sr * KP + sc] = ka.v;
      *(f16x8*)&Ks[sr * KP + sc + 8] = kb.v;
      const float* vg = Vf + (size_t)(kt * BC + sr) * HDIM + sc;
      float4 va = *(const float4*)(vg), vb = *(const float4*)(vg + 4);
      float4 vc = *(const float4*)(vg + 8), vd = *(const float4*)(vg + 12);
      float vv[16] = {va.x, va.y, va.z, va.w, vb.x, vb.y, vb.z, vb.w,
                      vc.x, vc.y, vc.z, vc.w, vd.x, vd.y, vd.z, vd.w};
      #pragma unroll
      for (int j = 0; j < 16; ++j) Vs[(sc + j) * KP + sr] = (_Float16)vv[j];
    }
  };

  f32x4 acc[2][4];
  #pragma unroll
  for (int h = 0; h < 2; ++h)
    #pragma unroll
    for (int nt = 0; nt < 4; ++nt)
      #pragma unroll
      for (int i = 0; i < 4; ++i) acc[h][nt][i] = 0.f;
  float m_[2] = {-1e30f, -1e30f};
  float l_[2] = {0.f, 0.f};

  prefetch(0);
  commit(0);

  for (int kt = 0; kt < SEQ / BC; ++kt) {
    __syncthreads();            // staged tile visible
    if (kt < SEQ / BC - 1) prefetch(kt + 1);

    // ---- S^T = K (Q*log2e)^T : D[kv=16jt+4g+ri][q=l16] ----
    f32x4 s[2][4];
    #pragma unroll
    for (int jt = 0; jt < 4; ++jt) {
      const int ka = (jt * 16 + l16) * KP + g * 8;
      f16x8 k0 = *(const f16x8*)&Ks[ka];
      f16x8 k1 = *(const f16x8*)&Ks[ka + 32];
      #pragma unroll
      for (int h = 0; h < 2; ++h) {
        f32x4 z;
        z[0] = z[1] = z[2] = z[3] = 0.f;
        z = __builtin_amdgcn_mfma_f32_16x16x32_f16(k0, qf[h][0], z, 0, 0, 0);
        z = __builtin_amdgcn_mfma_f32_16x16x32_f16(k1, qf[h][1], z, 0, 0, 0);
        s[h][jt] = z;
      }
    }

    // ---- online softmax over kv (per-lane 16 vals + 2 cross-g shuffles) ----
    #pragma unroll
    for (int h = 0; h < 2; ++h) {
      float mx = s[h][0][0];
      #pragma unroll
      for (int jt = 0; jt < 4; ++jt)
        #pragma unroll
        for (int ri = 0; ri < 4; ++ri) mx = fmaxf(mx, s[h][jt][ri]);
      mx = fmaxf(mx, __shfl_xor(mx, 16));
      mx = fmaxf(mx, __shfl_xor(mx, 32));
      float mnew = fmaxf(m_[h], mx);
      float al = fast_exp2(m_[h] - mnew);
      m_[h] = mnew;
      float psum = 0.f;
      _Float16* pw = &Ps[wave][h][l16 * PP + 4 * g];
      #pragma unroll
      for (int jt = 0; jt < 4; ++jt) {
        float p0 = fast_exp2(s[h][jt][0] - mnew);
        float p1 = fast_exp2(s[h][jt][1] - mnew);
        float p2 = fast_exp2(s[h][jt][2] - mnew);
        float p3 = fast_exp2(s[h][jt][3] - mnew);
        psum += (p0 + p1) + (p2 + p3);
        union { f16x4 v; f16x2 h2[2]; } u;
        u.h2[0] = pkrtz(p0, p1);
        u.h2[1] = pkrtz(p2, p3);
        *(f16x4*)(pw + jt * 16) = u.v;   // contiguous kv: b64 store
      }
      l_[h] = l_[h] * al + psum;
      // broadcast alpha from row-lanes (l16 = row) to acc rows (4g+ri)
      #pragma unroll
      for (int ri = 0; ri < 4; ++ri) {
        float aB = __shfl(al, 4 * g + ri);
        #pragma unroll
        for (int nt = 0; nt < 4; ++nt) acc[h][nt][ri] *= aB;
      }
    }

    // ---- O += P V  (A = P from Ps, B = V^T from Vs) ----
    f16x8 pa[2][2];
    #pragma unroll
    for (int h = 0; h < 2; ++h) {
      pa[h][0] = *(const f16x8*)&Ps[wave][h][l16 * PP + g * 8];
      pa[h][1] = *(const f16x8*)&Ps[wave][h][l16 * PP + g * 8 + 32];
    }
    #pragma unroll
    for (int nt = 0; nt < 4; ++nt) {
      const int va = (nt * 16 + l16) * KP + g * 8;
      f16x8 v0 = *(const f16x8*)&Vs[va];
      f16x8 v1 = *(const f16x8*)&Vs[va + 32];
      #pragma unroll
      for (int h = 0; h < 2; ++h) {
        acc[h][nt] = __builtin_amdgcn_mfma_f32_16x16x32_f16(pa[h][0], v0, acc[h][nt], 0, 0, 0);
        acc[h][nt] = __builtin_amdgcn_mfma_f32_16x16x32_f16(pa[h][1], v1, acc[h][nt], 0, 0, 0);
      }
    }

    __syncthreads();            // all Ks/Vs reads done
    if (kt < SEQ / BC - 1) commit(kt + 1);
  }

  // ---- epilogue: finish deferred row-sum, normalize, store ----
  #pragma unroll
  for (int h = 0; h < 2; ++h) {
    float lf = l_[h];
    lf += __shfl_xor(lf, 16);
    lf += __shfl_xor(lf, 32);
    float linv = 1.0f / lf;
    #pragma unroll
    for (int ri = 0; ri < 4; ++ri) {
      float lB = __shfl(linv, 4 * g + ri);
      const int row = qbase + h * 16 + 4 * g + ri;
      #pragma unroll
      for (int nt = 0; nt < 4; ++nt)
        O[(size_t)row * HDIM + nt * 16 + l16] = acc[h][nt][ri] * lB;
    }
  }
}

extern "C" void kernel_launch(void* const* d_in, const int* in_sizes, int n_in,
                              void* d_out, int out_size, void* d_ws, size_t ws_size,
                              hipStream_t stream) {
  const float* QKV = (const float*)d_in[0];
  float* Out = (float*)d_out;
  const size_t tensElems = (size_t)NHEADS * SEQ * HDIM;      // 4194304
  const size_t needBytes = tensElems * sizeof(_Float16);     // 8.39 MB

  dim3 block(256);
  dim3 grid(NHEADS * (SEQ / BR));  // 512

  if (ws_size >= needBytes) {
    _Float16* Vt16 = (_Float16*)d_ws;
    const float* V = QKV + 2 * tensElems;
    hipLaunchKernelGGL(conv_vt, dim3(NHEADS * (SEQ / 64)), block, 0, stream, V, Vt16);
    hipLaunchKernelGGL((flash_attn<true>), grid, block, 0, stream, QKV, Vt16, Out);
  } else {
    hipLaunchKernelGGL((flash_attn<false>), grid, block, 0, stream, QKV,
                       (const _Float16*)nullptr, Out);
  }
}

// Round 5
// 192.084 us; speedup vs baseline: 2.4195x; 1.0407x over previous
//
#include <hip/hip_runtime.h>

// Flash attention B=2,H=8,N=4096,d=64 fp32 in/out (QKV packed [3,16,4096,64]).
// Round 5: split-K (2 KV splits, flash-decoding style) to double resident
// waves (8 -> 16 per CU): round-4 was latency-bound (18.5% occupancy, no pipe
// >45%). Blocks write unnormalized O + (m,l) per row; combine kernel merges.
// Per-wave structure unchanged from round 4: S^T orientation, 32 q-rows/wave,
// deferred row-sum, b64 P stores, register-prefetch staging, V^T fp16 prepass.

typedef _Float16 f16x8 __attribute__((ext_vector_type(8)));
typedef _Float16 f16x4 __attribute__((ext_vector_type(4)));
typedef _Float16 f16x2 __attribute__((ext_vector_type(2)));
typedef float f32x4 __attribute__((ext_vector_type(4)));

#define NHEADS 16
#define SEQ 4096
#define HDIM 64
#define BR 128   // Q rows per block (4 waves x 32)
#define BC 64    // KV cols per iteration
#define KP 72    // LDS pitch (halves): 144B rows, 16B-aligned, 2-way banks
#define PP 72
#define NSPLIT 2

__device__ __forceinline__ float fast_exp2(float x) {
#if __has_builtin(__builtin_amdgcn_exp2f)
  return __builtin_amdgcn_exp2f(x);
#else
  return exp2f(x);
#endif
}

__device__ __forceinline__ f16x2 pkrtz(float a, float b) {
  return __builtin_bit_cast(f16x2, __builtin_amdgcn_cvt_pkrtz(a, b));
}

// ---- prepass: V fp32 [16][4096][64] -> fp16 transposed [16][64][4096] ----
__global__ __launch_bounds__(256) void conv_vt(const float* __restrict__ V,
                                               _Float16* __restrict__ Vt) {
  const int bh = blockIdx.x >> 6;
  const int nt = blockIdx.x & 63;
  __shared__ __align__(16) _Float16 T[64 * KP];
  const float* Vh = V + (size_t)bh * SEQ * HDIM + (size_t)nt * 64 * HDIM;
  const int t = threadIdx.x;
  #pragma unroll
  for (int p = 0; p < 4; ++p) {
    int idx = t + p * 256;
    int row = idx >> 4, c4 = (idx & 15) << 2;
    float4 v = *(const float4*)(Vh + row * HDIM + c4);
    union { f16x4 v4; f16x2 h2[2]; } h;
    h.h2[0] = pkrtz(v.x, v.y);
    h.h2[1] = pkrtz(v.z, v.w);
    *(f16x4*)&T[row * KP + c4] = h.v4;
  }
  __syncthreads();
  const int d = t & 63, w = t >> 6;
  f16x8 o0, o1;
  #pragma unroll
  for (int j = 0; j < 8; ++j) o0[j] = T[(w * 16 + j) * KP + d];
  #pragma unroll
  for (int j = 0; j < 8; ++j) o1[j] = T[(w * 16 + 8 + j) * KP + d];
  _Float16* out = Vt + (size_t)bh * HDIM * SEQ + (size_t)d * SEQ + nt * 64 + w * 16;
  *(f16x8*)out = o0;
  *(f16x8*)(out + 8) = o1;
}

// ---- combine: merge NSPLIT partials ----
// Opart: [split][16][4096][64] fp32 (unnormalized), Ml: [split][16*4096] float2
__global__ __launch_bounds__(256) void combine2(const float* __restrict__ Op,
                                                const float2* __restrict__ Ml,
                                                float* __restrict__ O) {
  const size_t tensElems = (size_t)NHEADS * SEQ * HDIM;
  size_t t = (size_t)blockIdx.x * 256 + threadIdx.x;  // 1,048,576 threads
  size_t row = t >> 4;
  int c = (int)(t & 15) << 2;
  float2 s0 = Ml[row];
  float2 s1 = Ml[(size_t)NHEADS * SEQ + row];
  float mstar = fmaxf(s0.x, s1.x);
  float w0 = fast_exp2(s0.x - mstar);
  float w1 = fast_exp2(s1.x - mstar);
  float inv = 1.0f / (w0 * s0.y + w1 * s1.y);
  float4 o0 = *(const float4*)(Op + row * HDIM + c);
  float4 o1 = *(const float4*)(Op + tensElems + row * HDIM + c);
  float4 r;
  r.x = (o0.x * w0 + o1.x * w1) * inv;
  r.y = (o0.y * w0 + o1.y * w1) * inv;
  r.z = (o0.z * w0 + o1.z * w1) * inv;
  r.w = (o0.w * w0 + o1.w * w1) * inv;
  *(float4*)(O + row * HDIM + c) = r;
}

// ---- main kernel ----
template <bool PRE, bool SPLIT>
__global__ __launch_bounds__(256, 4) void flash_attn(const float* __restrict__ QKV,
                                                     const _Float16* __restrict__ Vt16,
                                                     float* __restrict__ Out,
                                                     float* __restrict__ Opart,
                                                     float2* __restrict__ Ml) {
  const size_t headElems = (size_t)SEQ * HDIM;
  const size_t tensElems = (size_t)NHEADS * headElems;
  const int bh = blockIdx.x & 15;   // same-bh blocks 16 apart -> same XCD
  const int qt = blockIdx.x >> 4;   // 0..31
  const int split = SPLIT ? blockIdx.y : 0;
  const int ktBeg = SPLIT ? split * (SEQ / BC / NSPLIT) : 0;
  const int ktN = SPLIT ? (SEQ / BC / NSPLIT) : (SEQ / BC);

  const float* Q = QKV + (size_t)bh * headElems;
  const float* Kf = QKV + tensElems + (size_t)bh * headElems;
  const float* Vf = QKV + 2 * tensElems + (size_t)bh * headElems;
  const _Float16* Vg16 = Vt16 + (size_t)bh * headElems;  // [d][n]
  float* O = Out + (size_t)bh * headElems;

  const int tid = threadIdx.x;
  const int wave = tid >> 6;
  const int lane = tid & 63;
  const int g = lane >> 4;
  const int l16 = lane & 15;

  __shared__ __align__(16) _Float16 Ks[BC * KP];      // [kv][d]
  __shared__ __align__(16) _Float16 Vs[HDIM * KP];    // [d][kv]
  __shared__ __align__(16) _Float16 Ps[4][2][16 * PP];// [wave][h][q(l16)][kv]

  // ---- Q fragments (B operand of S^T): lane l16 = Q row, k = g*8+j ----
  const float LOG2E = 1.4426950408889634f;
  const int qbase = qt * BR + wave * 32;
  f16x8 qf[2][2];
  #pragma unroll
  for (int h = 0; h < 2; ++h) {
    const float* qp = Q + (size_t)(qbase + h * 16 + l16) * HDIM + g * 8;
    #pragma unroll
    for (int c = 0; c < 2; ++c) {
      float4 a = *(const float4*)(qp + c * 32);
      float4 b = *(const float4*)(qp + c * 32 + 4);
      union { f16x8 v; f16x2 h2[4]; } u;
      u.h2[0] = pkrtz(a.x * LOG2E, a.y * LOG2E);
      u.h2[1] = pkrtz(a.z * LOG2E, a.w * LOG2E);
      u.h2[2] = pkrtz(b.x * LOG2E, b.y * LOG2E);
      u.h2[3] = pkrtz(b.z * LOG2E, b.w * LOG2E);
      qf[h][c] = u.v;
    }
  }

  const int sr = tid >> 2;
  const int sc = (tid & 3) << 4;

  float4 kpre[4];
  f16x8 vpre[2];

  auto prefetch = [&](int kt) {
    if constexpr (PRE) {
      const float* kg = Kf + (size_t)(kt * BC + sr) * HDIM + sc;
      kpre[0] = *(const float4*)(kg);
      kpre[1] = *(const float4*)(kg + 4);
      kpre[2] = *(const float4*)(kg + 8);
      kpre[3] = *(const float4*)(kg + 12);
      const _Float16* vg = Vg16 + (size_t)sr * SEQ + kt * BC + sc;
      vpre[0] = *(const f16x8*)(vg);
      vpre[1] = *(const f16x8*)(vg + 8);
    }
  };
  auto commit = [&](int kt) {
    if constexpr (PRE) {
      union { f16x8 v; f16x2 h2[4]; } ka, kb;
      ka.h2[0] = pkrtz(kpre[0].x, kpre[0].y);
      ka.h2[1] = pkrtz(kpre[0].z, kpre[0].w);
      ka.h2[2] = pkrtz(kpre[1].x, kpre[1].y);
      ka.h2[3] = pkrtz(kpre[1].z, kpre[1].w);
      kb.h2[0] = pkrtz(kpre[2].x, kpre[2].y);
      kb.h2[1] = pkrtz(kpre[2].z, kpre[2].w);
      kb.h2[2] = pkrtz(kpre[3].x, kpre[3].y);
      kb.h2[3] = pkrtz(kpre[3].z, kpre[3].w);
      *(f16x8*)&Ks[sr * KP + sc] = ka.v;
      *(f16x8*)&Ks[sr * KP + sc + 8] = kb.v;
      *(f16x8*)&Vs[sr * KP + sc] = vpre[0];
      *(f16x8*)&Vs[sr * KP + sc + 8] = vpre[1];
    } else {
      const float* kg = Kf + (size_t)(kt * BC + sr) * HDIM + sc;
      float4 a = *(const float4*)(kg), b = *(const float4*)(kg + 4);
      float4 c = *(const float4*)(kg + 8), d = *(const float4*)(kg + 12);
      union { f16x8 v; f16x2 h2[4]; } ka, kb;
      ka.h2[0] = pkrtz(a.x, a.y);
      ka.h2[1] = pkrtz(a.z, a.w);
      ka.h2[2] = pkrtz(b.x, b.y);
      ka.h2[3] = pkrtz(b.z, b.w);
      kb.h2[0] = pkrtz(c.x, c.y);
      kb.h2[1] = pkrtz(c.z, c.w);
      kb.h2[2] = pkrtz(d.x, d.y);
      kb.h2[3] = pkrtz(d.z, d.w);
      *(f16x8*)&Ks[sr * KP + sc] = ka.v;
      *(f16x8*)&Ks[sr * KP + sc + 8] = kb.v;
      const float* vg = Vf + (size_t)(kt * BC + sr) * HDIM + sc;
      float4 va = *(const float4*)(vg), vb = *(const float4*)(vg + 4);
      float4 vc = *(const float4*)(vg + 8), vd = *(const float4*)(vg + 12);
      float vv[16] = {va.x, va.y, va.z, va.w, vb.x, vb.y, vb.z, vb.w,
                      vc.x, vc.y, vc.z, vc.w, vd.x, vd.y, vd.z, vd.w};
      #pragma unroll
      for (int j = 0; j < 16; ++j) Vs[(sc + j) * KP + sr] = (_Float16)vv[j];
    }
  };

  f32x4 acc[2][4];
  #pragma unroll
  for (int h = 0; h < 2; ++h)
    #pragma unroll
    for (int nt = 0; nt < 4; ++nt)
      #pragma unroll
      for (int i = 0; i < 4; ++i) acc[h][nt][i] = 0.f;
  float m_[2] = {-1e30f, -1e30f};
  float l_[2] = {0.f, 0.f};

  prefetch(ktBeg);
  commit(ktBeg);

  for (int it = 0; it < ktN; ++it) {
    const int kt = ktBeg + it;
    __syncthreads();            // staged tile visible
    if (it < ktN - 1) prefetch(kt + 1);

    // ---- S^T = K (Q*log2e)^T : D[kv=16jt+4g+ri][q=l16] ----
    f32x4 s[2][4];
    #pragma unroll
    for (int jt = 0; jt < 4; ++jt) {
      const int ka = (jt * 16 + l16) * KP + g * 8;
      f16x8 k0 = *(const f16x8*)&Ks[ka];
      f16x8 k1 = *(const f16x8*)&Ks[ka + 32];
      #pragma unroll
      for (int h = 0; h < 2; ++h) {
        f32x4 z;
        z[0] = z[1] = z[2] = z[3] = 0.f;
        z = __builtin_amdgcn_mfma_f32_16x16x32_f16(k0, qf[h][0], z, 0, 0, 0);
        z = __builtin_amdgcn_mfma_f32_16x16x32_f16(k1, qf[h][1], z, 0, 0, 0);
        s[h][jt] = z;
      }
    }

    // ---- online softmax over kv (per-lane 16 vals + 2 cross-g shuffles) ----
    #pragma unroll
    for (int h = 0; h < 2; ++h) {
      float mx = s[h][0][0];
      #pragma unroll
      for (int jt = 0; jt < 4; ++jt)
        #pragma unroll
        for (int ri = 0; ri < 4; ++ri) mx = fmaxf(mx, s[h][jt][ri]);
      mx = fmaxf(mx, __shfl_xor(mx, 16));
      mx = fmaxf(mx, __shfl_xor(mx, 32));
      float mnew = fmaxf(m_[h], mx);
      float al = fast_exp2(m_[h] - mnew);
      m_[h] = mnew;
      float psum = 0.f;
      _Float16* pw = &Ps[wave][h][l16 * PP + 4 * g];
      #pragma unroll
      for (int jt = 0; jt < 4; ++jt) {
        float p0 = fast_exp2(s[h][jt][0] - mnew);
        float p1 = fast_exp2(s[h][jt][1] - mnew);
        float p2 = fast_exp2(s[h][jt][2] - mnew);
        float p3 = fast_exp2(s[h][jt][3] - mnew);
        psum += (p0 + p1) + (p2 + p3);
        union { f16x4 v; f16x2 h2[2]; } u;
        u.h2[0] = pkrtz(p0, p1);
        u.h2[1] = pkrtz(p2, p3);
        *(f16x4*)(pw + jt * 16) = u.v;   // contiguous kv: b64 store
      }
      l_[h] = l_[h] * al + psum;
      #pragma unroll
      for (int ri = 0; ri < 4; ++ri) {
        float aB = __shfl(al, 4 * g + ri);
        #pragma unroll
        for (int nt = 0; nt < 4; ++nt) acc[h][nt][ri] *= aB;
      }
    }

    // ---- O += P V  (A = P from Ps, B = V^T from Vs) ----
    f16x8 pa[2][2];
    #pragma unroll
    for (int h = 0; h < 2; ++h) {
      pa[h][0] = *(const f16x8*)&Ps[wave][h][l16 * PP + g * 8];
      pa[h][1] = *(const f16x8*)&Ps[wave][h][l16 * PP + g * 8 + 32];
    }
    #pragma unroll
    for (int nt = 0; nt < 4; ++nt) {
      const int va = (nt * 16 + l16) * KP + g * 8;
      f16x8 v0 = *(const f16x8*)&Vs[va];
      f16x8 v1 = *(const f16x8*)&Vs[va + 32];
      #pragma unroll
      for (int h = 0; h < 2; ++h) {
        acc[h][nt] = __builtin_amdgcn_mfma_f32_16x16x32_f16(pa[h][0], v0, acc[h][nt], 0, 0, 0);
        acc[h][nt] = __builtin_amdgcn_mfma_f32_16x16x32_f16(pa[h][1], v1, acc[h][nt], 0, 0, 0);
      }
    }

    __syncthreads();            // all Ks/Vs reads done
    if (it < ktN - 1) commit(kt + 1);
  }

  // ---- epilogue ----
  #pragma unroll
  for (int h = 0; h < 2; ++h) {
    float lf = l_[h];
    lf += __shfl_xor(lf, 16);
    lf += __shfl_xor(lf, 32);
    if constexpr (SPLIT) {
      if (g == 0) {
        Ml[(size_t)split * NHEADS * SEQ + (size_t)bh * SEQ + qbase + h * 16 + l16] =
            float2{m_[h], lf};
      }
      #pragma unroll
      for (int ri = 0; ri < 4; ++ri) {
        const int row = qbase + h * 16 + 4 * g + ri;
        float* op = Opart + (size_t)split * tensElems + (size_t)bh * headElems;
        #pragma unroll
        for (int nt = 0; nt < 4; ++nt)
          op[(size_t)row * HDIM + nt * 16 + l16] = acc[h][nt][ri];
      }
    } else {
      float linv = 1.0f / lf;
      #pragma unroll
      for (int ri = 0; ri < 4; ++ri) {
        float lB = __shfl(linv, 4 * g + ri);
        const int row = qbase + h * 16 + 4 * g + ri;
        #pragma unroll
        for (int nt = 0; nt < 4; ++nt)
          O[(size_t)row * HDIM + nt * 16 + l16] = acc[h][nt][ri] * lB;
      }
    }
  }
}

extern "C" void kernel_launch(void* const* d_in, const int* in_sizes, int n_in,
                              void* d_out, int out_size, void* d_ws, size_t ws_size,
                              hipStream_t stream) {
  const float* QKV = (const float*)d_in[0];
  float* Out = (float*)d_out;
  const size_t tensElems = (size_t)NHEADS * SEQ * HDIM;        // 4,194,304
  const size_t vtBytes = tensElems * sizeof(_Float16);         // 8.39 MB
  const size_t opBytes = (size_t)NSPLIT * tensElems * 4;       // 33.55 MB
  const size_t mlBytes = (size_t)NSPLIT * NHEADS * SEQ * 8;    // 1.05 MB

  dim3 block(256);

  if (ws_size >= vtBytes + opBytes + mlBytes) {
    _Float16* Vt16 = (_Float16*)d_ws;
    float* Opart = (float*)((char*)d_ws + vtBytes);
    float2* Ml = (float2*)((char*)d_ws + vtBytes + opBytes);
    const float* V = QKV + 2 * tensElems;
    hipLaunchKernelGGL(conv_vt, dim3(NHEADS * (SEQ / 64)), block, 0, stream, V, Vt16);
    hipLaunchKernelGGL((flash_attn<true, true>), dim3(NHEADS * (SEQ / BR), NSPLIT),
                       block, 0, stream, QKV, Vt16, Out, Opart, Ml);
    hipLaunchKernelGGL(combine2, dim3((NHEADS * SEQ * HDIM / 4) / 256), block, 0,
                       stream, Opart, Ml, Out);
  } else if (ws_size >= vtBytes) {
    _Float16* Vt16 = (_Float16*)d_ws;
    const float* V = QKV + 2 * tensElems;
    hipLaunchKernelGGL(conv_vt, dim3(NHEADS * (SEQ / 64)), block, 0, stream, V, Vt16);
    hipLaunchKernelGGL((flash_attn<true, false>), dim3(NHEADS * (SEQ / BR)), block,
                       0, stream, QKV, Vt16, Out, (float*)nullptr, (float2*)nullptr);
  } else {
    hipLaunchKernelGGL((flash_attn<false, false>), dim3(NHEADS * (SEQ / BR)), block,
                       0, stream, QKV, (const _Float16*)nullptr, Out,
                       (float*)nullptr, (float2*)nullptr);
  }
}

// Round 7
// 186.414 us; speedup vs baseline: 2.4931x; 1.0304x over previous
//
#include <hip/hip_runtime.h>

// Flash attention B=2,H=8,N=4096,d=64 fp32 in/out (QKV packed [3,16,4096,64]).
// Round 7 = Round 6 (static-M softmax) with the clipping bug fixed: P and V
// are bf16 (range 2^127 -> exp2(s-M) never clips; fp16 P clipped at 2^16 and
// broke tail rows, absmax 5.36). QK^T stays fp16 MFMA; PV uses bf16 MFMA.
// Static M = tile0 row max + 4 folded into MFMA C-init; no online max /
// rescale; split-K 2 with normalized fp16 partials + combine kernel.

typedef _Float16 f16x8 __attribute__((ext_vector_type(8)));
typedef _Float16 f16x4 __attribute__((ext_vector_type(4)));
typedef _Float16 f16x2 __attribute__((ext_vector_type(2)));
typedef short s16x8 __attribute__((ext_vector_type(8)));
typedef short s16x4 __attribute__((ext_vector_type(4)));
typedef float f32x4 __attribute__((ext_vector_type(4)));

#define NHEADS 16
#define SEQ 4096
#define HDIM 64
#define BR 128   // Q rows per block (4 waves x 32)
#define BC 64    // KV cols per iteration
#define KP 72    // LDS pitch (halves): 144B rows, 16B-aligned, even bank spread
#define PP 72
#define NSPLIT 2
#define MPAD 4.0f  // M = tile0 row max + MPAD (log2 domain)

__device__ __forceinline__ float fast_exp2(float x) {
#if __has_builtin(__builtin_amdgcn_exp2f)
  return __builtin_amdgcn_exp2f(x);
#else
  return exp2f(x);
#endif
}

__device__ __forceinline__ f16x2 pkrtz(float a, float b) {
  return __builtin_bit_cast(f16x2, __builtin_amdgcn_cvt_pkrtz(a, b));
}

// fp32 -> bf16 round-to-nearest-even (for V prepass; once per element)
__device__ __forceinline__ unsigned short f2bf(float f) {
  unsigned u = __builtin_bit_cast(unsigned, f);
  u += 0x7fffu + ((u >> 16) & 1u);
  return (unsigned short)(u >> 16);
}

// pack two fp32 into two bf16 by truncation (3 VALU ops; safe & branchless).
// P>=0 so truncation loses <=2^-8 relative, consistent enough with fp32 l.
__device__ __forceinline__ unsigned bfpack2(float a, float b) {
  return (__builtin_bit_cast(unsigned, b) & 0xffff0000u) |
         (__builtin_bit_cast(unsigned, a) >> 16);
}

// ---- prepass: V fp32 [16][4096][64] -> bf16 transposed [16][64][4096] ----
__global__ __launch_bounds__(256) void conv_vt(const float* __restrict__ V,
                                               short* __restrict__ Vt) {
  const int bh = blockIdx.x >> 6;
  const int nt = blockIdx.x & 63;
  __shared__ __align__(16) short T[64 * KP];
  const float* Vh = V + (size_t)bh * SEQ * HDIM + (size_t)nt * 64 * HDIM;
  const int t = threadIdx.x;
  #pragma unroll
  for (int p = 0; p < 4; ++p) {
    int idx = t + p * 256;
    int row = idx >> 4, c4 = (idx & 15) << 2;
    float4 v = *(const float4*)(Vh + row * HDIM + c4);
    s16x4 h;
    h[0] = (short)f2bf(v.x); h[1] = (short)f2bf(v.y);
    h[2] = (short)f2bf(v.z); h[3] = (short)f2bf(v.w);
    *(s16x4*)&T[row * KP + c4] = h;
  }
  __syncthreads();
  const int d = t & 63, w = t >> 6;
  s16x8 o0, o1;
  #pragma unroll
  for (int j = 0; j < 8; ++j) o0[j] = T[(w * 16 + j) * KP + d];
  #pragma unroll
  for (int j = 0; j < 8; ++j) o1[j] = T[(w * 16 + 8 + j) * KP + d];
  short* out = Vt + (size_t)bh * HDIM * SEQ + (size_t)d * SEQ + nt * 64 + w * 16;
  *(s16x8*)out = o0;
  *(s16x8*)(out + 8) = o1;
}

// ---- combine: merge NSPLIT normalized fp16 partials ----
// Op: [split][16][4096][64] fp16 (normalized), Ml: [split][16*4096] (M, l)
__global__ __launch_bounds__(256) void combine2(const _Float16* __restrict__ Op,
                                                const float2* __restrict__ Ml,
                                                float* __restrict__ O) {
  const size_t tensElems = (size_t)NHEADS * SEQ * HDIM;
  size_t t = (size_t)blockIdx.x * 256 + threadIdx.x;  // 8 elems per thread
  size_t row = t >> 3;
  int seg = (int)(t & 7) << 3;
  float2 s0 = Ml[row];
  float2 s1 = Ml[(size_t)NHEADS * SEQ + row];
  float Ms = fmaxf(s0.x, s1.x);
  float a0 = fast_exp2(s0.x - Ms) * s0.y;
  float a1 = fast_exp2(s1.x - Ms) * s1.y;
  float inv = 1.0f / (a0 + a1);
  a0 *= inv;
  a1 *= inv;
  f16x8 o0 = *(const f16x8*)(Op + row * HDIM + seg);
  f16x8 o1 = *(const f16x8*)(Op + tensElems + row * HDIM + seg);
  float4 r0, r1;
  r0.x = (float)o0[0] * a0 + (float)o1[0] * a1;
  r0.y = (float)o0[1] * a0 + (float)o1[1] * a1;
  r0.z = (float)o0[2] * a0 + (float)o1[2] * a1;
  r0.w = (float)o0[3] * a0 + (float)o1[3] * a1;
  r1.x = (float)o0[4] * a0 + (float)o1[4] * a1;
  r1.y = (float)o0[5] * a0 + (float)o1[5] * a1;
  r1.z = (float)o0[6] * a0 + (float)o1[6] * a1;
  r1.w = (float)o0[7] * a0 + (float)o1[7] * a1;
  *(float4*)(O + row * HDIM + seg) = r0;
  *(float4*)(O + row * HDIM + seg + 4) = r1;
}

// ---- main kernel ----
template <bool PRE, bool SPLIT>
__global__ __launch_bounds__(256, 4) void flash_attn(const float* __restrict__ QKV,
                                                     const short* __restrict__ Vt16,
                                                     float* __restrict__ Out,
                                                     _Float16* __restrict__ Opart,
                                                     float2* __restrict__ Ml) {
  const size_t headElems = (size_t)SEQ * HDIM;
  const size_t tensElems = (size_t)NHEADS * headElems;
  const int bh = blockIdx.x & 15;   // same-bh blocks 16 apart -> same XCD
  const int qt = blockIdx.x >> 4;   // 0..31
  const int split = SPLIT ? blockIdx.y : 0;
  const int ktBeg = SPLIT ? split * (SEQ / BC / NSPLIT) : 0;
  const int ktN = SPLIT ? (SEQ / BC / NSPLIT) : (SEQ / BC);

  const float* Q = QKV + (size_t)bh * headElems;
  const float* Kf = QKV + tensElems + (size_t)bh * headElems;
  const float* Vf = QKV + 2 * tensElems + (size_t)bh * headElems;
  const short* Vg16 = Vt16 + (size_t)bh * headElems;  // [d][n] bf16
  float* O = Out + (size_t)bh * headElems;

  const int tid = threadIdx.x;
  const int wave = tid >> 6;
  const int lane = tid & 63;
  const int g = lane >> 4;
  const int l16 = lane & 15;

  __shared__ __align__(16) _Float16 Ks[BC * KP];   // [kv][d] fp16
  __shared__ __align__(16) short Vs[HDIM * KP];    // [d][kv] bf16
  __shared__ __align__(16) short Ps[4][2][16 * PP];// [wave][h][q(l16)][kv] bf16

  // ---- Q fragments (B operand of S^T): lane l16 = Q row, k = g*8+j ----
  const float LOG2E = 1.4426950408889634f;
  const int qbase = qt * BR + wave * 32;
  f16x8 qf[2][2];
  #pragma unroll
  for (int h = 0; h < 2; ++h) {
    const float* qp = Q + (size_t)(qbase + h * 16 + l16) * HDIM + g * 8;
    #pragma unroll
    for (int c = 0; c < 2; ++c) {
      float4 a = *(const float4*)(qp + c * 32);
      float4 b = *(const float4*)(qp + c * 32 + 4);
      union { f16x8 v; f16x2 h2[4]; } u;
      u.h2[0] = pkrtz(a.x * LOG2E, a.y * LOG2E);
      u.h2[1] = pkrtz(a.z * LOG2E, a.w * LOG2E);
      u.h2[2] = pkrtz(b.x * LOG2E, b.y * LOG2E);
      u.h2[3] = pkrtz(b.z * LOG2E, b.w * LOG2E);
      qf[h][c] = u.v;
    }
  }

  const int sr = tid >> 2;
  const int sc = (tid & 3) << 4;

  float4 kpre[4];
  s16x8 vpre[2];

  auto prefetch = [&](int kt) {
    if constexpr (PRE) {
      const float* kg = Kf + (size_t)(kt * BC + sr) * HDIM + sc;
      kpre[0] = *(const float4*)(kg);
      kpre[1] = *(const float4*)(kg + 4);
      kpre[2] = *(const float4*)(kg + 8);
      kpre[3] = *(const float4*)(kg + 12);
      const short* vg = Vg16 + (size_t)sr * SEQ + kt * BC + sc;
      vpre[0] = *(const s16x8*)(vg);
      vpre[1] = *(const s16x8*)(vg + 8);
    }
  };
  auto commit = [&](int kt) {
    if constexpr (PRE) {
      union { f16x8 v; f16x2 h2[4]; } ka, kb;
      ka.h2[0] = pkrtz(kpre[0].x, kpre[0].y);
      ka.h2[1] = pkrtz(kpre[0].z, kpre[0].w);
      ka.h2[2] = pkrtz(kpre[1].x, kpre[1].y);
      ka.h2[3] = pkrtz(kpre[1].z, kpre[1].w);
      kb.h2[0] = pkrtz(kpre[2].x, kpre[2].y);
      kb.h2[1] = pkrtz(kpre[2].z, kpre[2].w);
      kb.h2[2] = pkrtz(kpre[3].x, kpre[3].y);
      kb.h2[3] = pkrtz(kpre[3].z, kpre[3].w);
      *(f16x8*)&Ks[sr * KP + sc] = ka.v;
      *(f16x8*)&Ks[sr * KP + sc + 8] = kb.v;
      *(s16x8*)&Vs[sr * KP + sc] = vpre[0];
      *(s16x8*)&Vs[sr * KP + sc + 8] = vpre[1];
    } else {
      const float* kg = Kf + (size_t)(kt * BC + sr) * HDIM + sc;
      float4 a = *(const float4*)(kg), b = *(const float4*)(kg + 4);
      float4 c = *(const float4*)(kg + 8), d = *(const float4*)(kg + 12);
      union { f16x8 v; f16x2 h2[4]; } ka, kb;
      ka.h2[0] = pkrtz(a.x, a.y);
      ka.h2[1] = pkrtz(a.z, a.w);
      ka.h2[2] = pkrtz(b.x, b.y);
      ka.h2[3] = pkrtz(b.z, b.w);
      kb.h2[0] = pkrtz(c.x, c.y);
      kb.h2[1] = pkrtz(c.z, c.w);
      kb.h2[2] = pkrtz(d.x, d.y);
      kb.h2[3] = pkrtz(d.z, d.w);
      *(f16x8*)&Ks[sr * KP + sc] = ka.v;
      *(f16x8*)&Ks[sr * KP + sc + 8] = kb.v;
      const float* vg = Vf + (size_t)(kt * BC + sr) * HDIM + sc;
      float4 va = *(const float4*)(vg), vb = *(const float4*)(vg + 4);
      float4 vc = *(const float4*)(vg + 8), vd = *(const float4*)(vg + 12);
      float vv[16] = {va.x, va.y, va.z, va.w, vb.x, vb.y, vb.z, vb.w,
                      vc.x, vc.y, vc.z, vc.w, vd.x, vd.y, vd.z, vd.w};
      #pragma unroll
      for (int j = 0; j < 16; ++j) Vs[(sc + j) * KP + sr] = (short)f2bf(vv[j]);
    }
  };

  f32x4 acc[2][4];
  #pragma unroll
  for (int h = 0; h < 2; ++h)
    #pragma unroll
    for (int nt = 0; nt < 4; ++nt)
      #pragma unroll
      for (int i = 0; i < 4; ++i) acc[h][nt][i] = 0.f;
  float l_[2] = {0.f, 0.f};
  float negM[2] = {0.f, 0.f};  // 0 for tile 0 (raw scores), then -M

  prefetch(ktBeg);
  commit(ktBeg);

  for (int it = 0; it < ktN; ++it) {
    const int kt = ktBeg + it;
    __syncthreads();            // staged tile visible
    if (it < ktN - 1) prefetch(kt + 1);

    // ---- S^T - M = K (Q*log2e)^T + C(-M) : D[kv=16jt+4g+ri][q=l16] ----
    f32x4 s[2][4];
    #pragma unroll
    for (int jt = 0; jt < 4; ++jt) {
      const int ka = (jt * 16 + l16) * KP + g * 8;
      f16x8 k0 = *(const f16x8*)&Ks[ka];
      f16x8 k1 = *(const f16x8*)&Ks[ka + 32];
      #pragma unroll
      for (int h = 0; h < 2; ++h) {
        f32x4 z;
        z[0] = z[1] = z[2] = z[3] = negM[h];   // -M folded into C
        z = __builtin_amdgcn_mfma_f32_16x16x32_f16(k0, qf[h][0], z, 0, 0, 0);
        z = __builtin_amdgcn_mfma_f32_16x16x32_f16(k1, qf[h][1], z, 0, 0, 0);
        s[h][jt] = z;
      }
    }

    // ---- tile 0 only: derive per-row static M from this tile's max ----
    if (it == 0) {
      #pragma unroll
      for (int h = 0; h < 2; ++h) {
        float mx = s[h][0][0];
        #pragma unroll
        for (int jt = 0; jt < 4; ++jt)
          #pragma unroll
          for (int ri = 0; ri < 4; ++ri) mx = fmaxf(mx, s[h][jt][ri]);
        mx = fmaxf(mx, __shfl_xor(mx, 16));
        mx = fmaxf(mx, __shfl_xor(mx, 32));
        negM[h] = -(mx + MPAD);
        #pragma unroll
        for (int jt = 0; jt < 4; ++jt)
          #pragma unroll
          for (int ri = 0; ri < 4; ++ri) s[h][jt][ri] += negM[h];
      }
    }

    // ---- P = exp2(S - M) in bf16 (never clips), fp32 psum ----
    #pragma unroll
    for (int h = 0; h < 2; ++h) {
      float psum = l_[h];
      const int e0 = l16 * PP + 4 * g;
      #pragma unroll
      for (int jt = 0; jt < 4; ++jt) {
        float p0 = fast_exp2(s[h][jt][0]);
        float p1 = fast_exp2(s[h][jt][1]);
        float p2 = fast_exp2(s[h][jt][2]);
        float p3 = fast_exp2(s[h][jt][3]);
        psum += (p0 + p1) + (p2 + p3);
        uint2 w;
        w.x = bfpack2(p0, p1);
        w.y = bfpack2(p2, p3);
        *(uint2*)&Ps[wave][h][e0 + jt * 16] = w;   // contiguous kv: b64 store
      }
      l_[h] = psum;
    }

    // ---- O += P V  (A = P bf16 from Ps, B = V^T bf16 from Vs) ----
    s16x8 pa[2][2];
    #pragma unroll
    for (int h = 0; h < 2; ++h) {
      pa[h][0] = *(const s16x8*)&Ps[wave][h][l16 * PP + g * 8];
      pa[h][1] = *(const s16x8*)&Ps[wave][h][l16 * PP + g * 8 + 32];
    }
    #pragma unroll
    for (int nt = 0; nt < 4; ++nt) {
      const int va = (nt * 16 + l16) * KP + g * 8;
      s16x8 v0 = *(const s16x8*)&Vs[va];
      s16x8 v1 = *(const s16x8*)&Vs[va + 32];
      #pragma unroll
      for (int h = 0; h < 2; ++h) {
        acc[h][nt] = __builtin_amdgcn_mfma_f32_16x16x32_bf16(pa[h][0], v0, acc[h][nt], 0, 0, 0);
        acc[h][nt] = __builtin_amdgcn_mfma_f32_16x16x32_bf16(pa[h][1], v1, acc[h][nt], 0, 0, 0);
      }
    }

    __syncthreads();            // all Ks/Vs reads done
    if (it < ktN - 1) commit(kt + 1);
  }

  // ---- epilogue ----
  #pragma unroll
  for (int h = 0; h < 2; ++h) {
    float lf = l_[h];
    lf += __shfl_xor(lf, 16);
    lf += __shfl_xor(lf, 32);
    float linv = 1.0f / lf;
    if constexpr (SPLIT) {
      if (g == 0) {
        Ml[(size_t)split * NHEADS * SEQ + (size_t)bh * SEQ + qbase + h * 16 + l16] =
            float2{-negM[h], lf};
      }
      _Float16* op = Opart + (size_t)split * tensElems + (size_t)bh * headElems;
      #pragma unroll
      for (int ri = 0; ri < 4; ++ri) {
        float lB = __shfl(linv, 4 * g + ri);
        const int row = qbase + h * 16 + 4 * g + ri;
        #pragma unroll
        for (int nt = 0; nt < 4; ++nt)
          op[(size_t)row * HDIM + nt * 16 + l16] = (_Float16)(acc[h][nt][ri] * lB);
      }
    } else {
      #pragma unroll
      for (int ri = 0; ri < 4; ++ri) {
        float lB = __shfl(linv, 4 * g + ri);
        const int row = qbase + h * 16 + 4 * g + ri;
        #pragma unroll
        for (int nt = 0; nt < 4; ++nt)
          O[(size_t)row * HDIM + nt * 16 + l16] = acc[h][nt][ri] * lB;
      }
    }
  }
}

extern "C" void kernel_launch(void* const* d_in, const int* in_sizes, int n_in,
                              void* d_out, int out_size, void* d_ws, size_t ws_size,
                              hipStream_t stream) {
  const float* QKV = (const float*)d_in[0];
  float* Out = (float*)d_out;
  const size_t tensElems = (size_t)NHEADS * SEQ * HDIM;             // 4,194,304
  const size_t vtBytes = tensElems * sizeof(short);                 // 8.39 MB
  const size_t opBytes = (size_t)NSPLIT * tensElems * sizeof(_Float16);  // 16.78 MB
  const size_t mlBytes = (size_t)NSPLIT * NHEADS * SEQ * 8;         // 1.05 MB

  dim3 block(256);

  if (ws_size >= vtBytes + opBytes + mlBytes) {
    short* Vt16 = (short*)d_ws;
    _Float16* Opart = (_Float16*)((char*)d_ws + vtBytes);
    float2* Ml = (float2*)((char*)d_ws + vtBytes + opBytes);
    const float* V = QKV + 2 * tensElems;
    hipLaunchKernelGGL(conv_vt, dim3(NHEADS * (SEQ / 64)), block, 0, stream, V, Vt16);
    hipLaunchKernelGGL((flash_attn<true, true>), dim3(NHEADS * (SEQ / BR), NSPLIT),
                       block, 0, stream, QKV, Vt16, Out, Opart, Ml);
    hipLaunchKernelGGL(combine2, dim3((NHEADS * SEQ * HDIM / 8) / 256), block, 0,
                       stream, Opart, Ml, Out);
  } else if (ws_size >= vtBytes) {
    short* Vt16 = (short*)d_ws;
    const float* V = QKV + 2 * tensElems;
    hipLaunchKernelGGL(conv_vt, dim3(NHEADS * (SEQ / 64)), block, 0, stream, V, Vt16);
    hipLaunchKernelGGL((flash_attn<true, false>), dim3(NHEADS * (SEQ / BR)), block,
                       0, stream, QKV, Vt16, Out, (_Float16*)nullptr, (float2*)nullptr);
  } else {
    hipLaunchKernelGGL((flash_attn<false, false>), dim3(NHEADS * (SEQ / BR)), block,
                       0, stream, QKV, (const short*)nullptr, Out,
                       (_Float16*)nullptr, (float2*)nullptr);
  }
}

// Round 8
// 170.708 us; speedup vs baseline: 2.7224x; 1.0920x over previous
//
#include <hip/hip_runtime.h>

// Flash attention B=2,H=8,N=4096,d=64 fp32 in/out (QKV packed [3,16,4096,64]).
// Round 8: DS-traffic cut. Round 7 was DS-pipe-bound (~70us/CU of LDS traffic
// vs 30us MFMA): K/V fragment reads dominate and are q-independent per wave,
// so each wave now owns 64 q rows (BR=256, 4 h-tiles) halving frag bytes per
// unit work (~45us/CU). K is pre-converted to fp16 in a fused prepass (with
// the V bf16 transpose) so staging is pure vector copies. Retained from r7:
// static-M softmax (M = tile0 max + 4 folded into MFMA C-init), bf16 P/V
// (no fp16 clipping), split-K 2 with normalized fp16 partials + combine.

typedef _Float16 f16x8 __attribute__((ext_vector_type(8)));
typedef _Float16 f16x2 __attribute__((ext_vector_type(2)));
typedef short s16x8 __attribute__((ext_vector_type(8)));
typedef short s16x4 __attribute__((ext_vector_type(4)));
typedef float f32x4 __attribute__((ext_vector_type(4)));

#define NHEADS 16
#define SEQ 4096
#define HDIM 64
#define BR 256   // Q rows per block (4 waves x 64)
#define NH 4     // 16-row h-tiles per wave
#define BC 64    // KV cols per iteration
#define KP 72    // LDS pitch (halves): 144B rows, 16B-aligned, 2-way banks
#define PP 72
#define NSPLIT 2
#define MPAD 4.0f  // M = tile0 row max + MPAD (log2 domain)

__device__ __forceinline__ float fast_exp2(float x) {
#if __has_builtin(__builtin_amdgcn_exp2f)
  return __builtin_amdgcn_exp2f(x);
#else
  return exp2f(x);
#endif
}

__device__ __forceinline__ f16x2 pkrtz(float a, float b) {
  return __builtin_bit_cast(f16x2, __builtin_amdgcn_cvt_pkrtz(a, b));
}

// fp32 -> bf16 RNE (prepass only)
__device__ __forceinline__ unsigned short f2bf(float f) {
  unsigned u = __builtin_bit_cast(unsigned, f);
  u += 0x7fffu + ((u >> 16) & 1u);
  return (unsigned short)(u >> 16);
}

// two fp32 -> two bf16 by truncation (P >= 0; consistent with fp32 psum)
__device__ __forceinline__ unsigned bfpack2(float a, float b) {
  return (__builtin_bit_cast(unsigned, b) & 0xffff0000u) |
         (__builtin_bit_cast(unsigned, a) >> 16);
}

// ---- fused prepass ----
// blocks [0, 2048):  K fp32 -> fp16, layout preserved [16][4096][64]
// blocks [2048, 3072): V fp32 [16][4096][64] -> bf16 transposed [16][64][4096]
__global__ __launch_bounds__(256) void prep(const float* __restrict__ QKV,
                                            _Float16* __restrict__ K16,
                                            short* __restrict__ Vt) {
  const size_t tensElems = (size_t)NHEADS * SEQ * HDIM;
  __shared__ __align__(16) short T[64 * KP];
  if (blockIdx.x < 2048) {
    const float* Kf = QKV + tensElems;
    size_t i = ((size_t)blockIdx.x * 256 + threadIdx.x) * 8;
    float4 a = *(const float4*)(Kf + i);
    float4 b = *(const float4*)(Kf + i + 4);
    union { f16x8 v; f16x2 h2[4]; } u;
    u.h2[0] = pkrtz(a.x, a.y);
    u.h2[1] = pkrtz(a.z, a.w);
    u.h2[2] = pkrtz(b.x, b.y);
    u.h2[3] = pkrtz(b.z, b.w);
    *(f16x8*)(K16 + i) = u.v;
  } else {
    const int vb = blockIdx.x - 2048;
    const int bh = vb >> 6;
    const int nt = vb & 63;
    const float* Vh = QKV + 2 * tensElems + (size_t)bh * SEQ * HDIM +
                      (size_t)nt * 64 * HDIM;
    const int t = threadIdx.x;
    #pragma unroll
    for (int p = 0; p < 4; ++p) {
      int idx = t + p * 256;
      int row = idx >> 4, c4 = (idx & 15) << 2;
      float4 v = *(const float4*)(Vh + row * HDIM + c4);
      s16x4 h;
      h[0] = (short)f2bf(v.x); h[1] = (short)f2bf(v.y);
      h[2] = (short)f2bf(v.z); h[3] = (short)f2bf(v.w);
      *(s16x4*)&T[row * KP + c4] = h;
    }
    __syncthreads();
    const int d = t & 63, w = t >> 6;
    s16x8 o0, o1;
    #pragma unroll
    for (int j = 0; j < 8; ++j) o0[j] = T[(w * 16 + j) * KP + d];
    #pragma unroll
    for (int j = 0; j < 8; ++j) o1[j] = T[(w * 16 + 8 + j) * KP + d];
    short* out = Vt + (size_t)bh * HDIM * SEQ + (size_t)d * SEQ + nt * 64 + w * 16;
    *(s16x8*)out = o0;
    *(s16x8*)(out + 8) = o1;
  }
}

// ---- combine: merge NSPLIT normalized fp16 partials ----
__global__ __launch_bounds__(256) void combine2(const _Float16* __restrict__ Op,
                                                const float2* __restrict__ Ml,
                                                float* __restrict__ O) {
  const size_t tensElems = (size_t)NHEADS * SEQ * HDIM;
  size_t t = (size_t)blockIdx.x * 256 + threadIdx.x;  // 8 elems per thread
  size_t row = t >> 3;
  int seg = (int)(t & 7) << 3;
  float2 s0 = Ml[row];
  float2 s1 = Ml[(size_t)NHEADS * SEQ + row];
  float Ms = fmaxf(s0.x, s1.x);
  float a0 = fast_exp2(s0.x - Ms) * s0.y;
  float a1 = fast_exp2(s1.x - Ms) * s1.y;
  float inv = 1.0f / (a0 + a1);
  a0 *= inv;
  a1 *= inv;
  f16x8 o0 = *(const f16x8*)(Op + row * HDIM + seg);
  f16x8 o1 = *(const f16x8*)(Op + tensElems + row * HDIM + seg);
  float4 r0, r1;
  r0.x = (float)o0[0] * a0 + (float)o1[0] * a1;
  r0.y = (float)o0[1] * a0 + (float)o1[1] * a1;
  r0.z = (float)o0[2] * a0 + (float)o1[2] * a1;
  r0.w = (float)o0[3] * a0 + (float)o1[3] * a1;
  r1.x = (float)o0[4] * a0 + (float)o1[4] * a1;
  r1.y = (float)o0[5] * a0 + (float)o1[5] * a1;
  r1.z = (float)o0[6] * a0 + (float)o1[6] * a1;
  r1.w = (float)o0[7] * a0 + (float)o1[7] * a1;
  *(float4*)(O + row * HDIM + seg) = r0;
  *(float4*)(O + row * HDIM + seg + 4) = r1;
}

// ---- main kernel ----
template <bool PRE, bool SPLIT>
__global__ __launch_bounds__(256, 2) void flash_attn(const float* __restrict__ QKV,
                                                     const _Float16* __restrict__ K16g,
                                                     const short* __restrict__ Vt16,
                                                     float* __restrict__ Out,
                                                     _Float16* __restrict__ Opart,
                                                     float2* __restrict__ Ml) {
  const size_t headElems = (size_t)SEQ * HDIM;
  const size_t tensElems = (size_t)NHEADS * headElems;
  const int bh = blockIdx.x & 15;   // same-bh blocks 16 apart -> same XCD
  const int qt = blockIdx.x >> 4;   // 0..15
  const int split = SPLIT ? blockIdx.y : 0;
  const int ktBeg = SPLIT ? split * (SEQ / BC / NSPLIT) : 0;
  const int ktN = SPLIT ? (SEQ / BC / NSPLIT) : (SEQ / BC);

  const float* Q = QKV + (size_t)bh * headElems;
  const float* Kf = QKV + tensElems + (size_t)bh * headElems;
  const float* Vf = QKV + 2 * tensElems + (size_t)bh * headElems;
  const _Float16* Kg16 = K16g + (size_t)bh * headElems;  // [n][d] fp16
  const short* Vg16 = Vt16 + (size_t)bh * headElems;     // [d][n] bf16
  float* O = Out + (size_t)bh * headElems;

  const int tid = threadIdx.x;
  const int wave = tid >> 6;
  const int lane = tid & 63;
  const int g = lane >> 4;
  const int l16 = lane & 15;

  __shared__ __align__(16) _Float16 Ks[BC * KP];    // [kv][d] fp16   9216 B
  __shared__ __align__(16) short Vs[HDIM * KP];     // [d][kv] bf16   9216 B
  __shared__ __align__(16) short Ps[4][NH][16 * PP];// bf16          36864 B

  // ---- Q fragments (B operand of S^T): lane l16 = Q row, k = g*8+j ----
  const float LOG2E = 1.4426950408889634f;
  const int qbase = qt * BR + wave * (16 * NH);
  f16x8 qf[NH][2];
  #pragma unroll
  for (int h = 0; h < NH; ++h) {
    const float* qp = Q + (size_t)(qbase + h * 16 + l16) * HDIM + g * 8;
    #pragma unroll
    for (int c = 0; c < 2; ++c) {
      float4 a = *(const float4*)(qp + c * 32);
      float4 b = *(const float4*)(qp + c * 32 + 4);
      union { f16x8 v; f16x2 h2[4]; } u;
      u.h2[0] = pkrtz(a.x * LOG2E, a.y * LOG2E);
      u.h2[1] = pkrtz(a.z * LOG2E, a.w * LOG2E);
      u.h2[2] = pkrtz(b.x * LOG2E, b.y * LOG2E);
      u.h2[3] = pkrtz(b.z * LOG2E, b.w * LOG2E);
      qf[h][c] = u.v;
    }
  }

  const int sr = tid >> 2;          // staged row 0..63
  const int sc = (tid & 3) << 4;    // staged col 0,16,32,48

  s16x8 kpre[2];   // fp16 bits held as shorts
  s16x8 vpre[2];

  auto prefetch = [&](int kt) {
    if constexpr (PRE) {
      const _Float16* kg = Kg16 + (size_t)(kt * BC + sr) * HDIM + sc;
      kpre[0] = *(const s16x8*)(kg);
      kpre[1] = *(const s16x8*)(kg + 8);
      const short* vg = Vg16 + (size_t)sr * SEQ + kt * BC + sc;
      vpre[0] = *(const s16x8*)(vg);
      vpre[1] = *(const s16x8*)(vg + 8);
    }
  };
  auto commit = [&](int kt) {
    if constexpr (PRE) {
      *(s16x8*)&Ks[sr * KP + sc] = kpre[0];
      *(s16x8*)&Ks[sr * KP + sc + 8] = kpre[1];
      *(s16x8*)&Vs[sr * KP + sc] = vpre[0];
      *(s16x8*)&Vs[sr * KP + sc + 8] = vpre[1];
    } else {
      const float* kg = Kf + (size_t)(kt * BC + sr) * HDIM + sc;
      float4 a = *(const float4*)(kg), b = *(const float4*)(kg + 4);
      float4 c = *(const float4*)(kg + 8), d = *(const float4*)(kg + 12);
      union { f16x8 v; f16x2 h2[4]; } ka, kb;
      ka.h2[0] = pkrtz(a.x, a.y);
      ka.h2[1] = pkrtz(a.z, a.w);
      ka.h2[2] = pkrtz(b.x, b.y);
      ka.h2[3] = pkrtz(b.z, b.w);
      kb.h2[0] = pkrtz(c.x, c.y);
      kb.h2[1] = pkrtz(c.z, c.w);
      kb.h2[2] = pkrtz(d.x, d.y);
      kb.h2[3] = pkrtz(d.z, d.w);
      *(f16x8*)&Ks[sr * KP + sc] = ka.v;
      *(f16x8*)&Ks[sr * KP + sc + 8] = kb.v;
      const float* vg = Vf + (size_t)(kt * BC + sr) * HDIM + sc;
      float4 va = *(const float4*)(vg), vb = *(const float4*)(vg + 4);
      float4 vc = *(const float4*)(vg + 8), vd = *(const float4*)(vg + 12);
      float vv[16] = {va.x, va.y, va.z, va.w, vb.x, vb.y, vb.z, vb.w,
                      vc.x, vc.y, vc.z, vc.w, vd.x, vd.y, vd.z, vd.w};
      #pragma unroll
      for (int j = 0; j < 16; ++j) Vs[(sc + j) * KP + sr] = (short)f2bf(vv[j]);
    }
  };

  f32x4 acc[NH][4];
  #pragma unroll
  for (int h = 0; h < NH; ++h)
    #pragma unroll
    for (int nt = 0; nt < 4; ++nt)
      #pragma unroll
      for (int i = 0; i < 4; ++i) acc[h][nt][i] = 0.f;
  float l_[NH] = {0.f, 0.f, 0.f, 0.f};
  float negM[NH] = {0.f, 0.f, 0.f, 0.f};  // 0 for tile 0, then -M

  prefetch(ktBeg);
  commit(ktBeg);

  for (int it = 0; it < ktN; ++it) {
    const int kt = ktBeg + it;
    __syncthreads();            // staged tile visible
    if (it < ktN - 1) prefetch(kt + 1);

    // ---- S^T - M = K (Q*log2e)^T + C(-M) : D[kv=16jt+4g+ri][q=l16] ----
    f32x4 s[NH][4];
    #pragma unroll
    for (int jt = 0; jt < 4; ++jt) {
      const int ka = (jt * 16 + l16) * KP + g * 8;
      f16x8 k0 = *(const f16x8*)&Ks[ka];
      f16x8 k1 = *(const f16x8*)&Ks[ka + 32];
      #pragma unroll
      for (int h = 0; h < NH; ++h) {
        f32x4 z;
        z[0] = z[1] = z[2] = z[3] = negM[h];   // -M folded into C
        z = __builtin_amdgcn_mfma_f32_16x16x32_f16(k0, qf[h][0], z, 0, 0, 0);
        z = __builtin_amdgcn_mfma_f32_16x16x32_f16(k1, qf[h][1], z, 0, 0, 0);
        s[h][jt] = z;
      }
    }

    // ---- tile 0 only: derive per-row static M ----
    if (it == 0) {
      #pragma unroll
      for (int h = 0; h < NH; ++h) {
        float mx = s[h][0][0];
        #pragma unroll
        for (int jt = 0; jt < 4; ++jt)
          #pragma unroll
          for (int ri = 0; ri < 4; ++ri) mx = fmaxf(mx, s[h][jt][ri]);
        mx = fmaxf(mx, __shfl_xor(mx, 16));
        mx = fmaxf(mx, __shfl_xor(mx, 32));
        negM[h] = -(mx + MPAD);
        #pragma unroll
        for (int jt = 0; jt < 4; ++jt)
          #pragma unroll
          for (int ri = 0; ri < 4; ++ri) s[h][jt][ri] += negM[h];
      }
    }

    // ---- P = exp2(S - M) in bf16 (never clips), fp32 psum ----
    #pragma unroll
    for (int h = 0; h < NH; ++h) {
      float psum = l_[h];
      const int e0 = l16 * PP + 4 * g;
      #pragma unroll
      for (int jt = 0; jt < 4; ++jt) {
        float p0 = fast_exp2(s[h][jt][0]);
        float p1 = fast_exp2(s[h][jt][1]);
        float p2 = fast_exp2(s[h][jt][2]);
        float p3 = fast_exp2(s[h][jt][3]);
        psum += (p0 + p1) + (p2 + p3);
        uint2 w;
        w.x = bfpack2(p0, p1);
        w.y = bfpack2(p2, p3);
        *(uint2*)&Ps[wave][h][e0 + jt * 16] = w;   // contiguous kv: b64 store
      }
      l_[h] = psum;
    }

    // ---- O += P V  (A = P bf16, B = V^T bf16) ----
    s16x8 pa[NH][2];
    #pragma unroll
    for (int h = 0; h < NH; ++h) {
      pa[h][0] = *(const s16x8*)&Ps[wave][h][l16 * PP + g * 8];
      pa[h][1] = *(const s16x8*)&Ps[wave][h][l16 * PP + g * 8 + 32];
    }
    #pragma unroll
    for (int nt = 0; nt < 4; ++nt) {
      const int va = (nt * 16 + l16) * KP + g * 8;
      s16x8 v0 = *(const s16x8*)&Vs[va];
      s16x8 v1 = *(const s16x8*)&Vs[va + 32];
      #pragma unroll
      for (int h = 0; h < NH; ++h) {
        acc[h][nt] = __builtin_amdgcn_mfma_f32_16x16x32_bf16(pa[h][0], v0, acc[h][nt], 0, 0, 0);
        acc[h][nt] = __builtin_amdgcn_mfma_f32_16x16x32_bf16(pa[h][1], v1, acc[h][nt], 0, 0, 0);
      }
    }

    __syncthreads();            // all Ks/Vs reads done
    if (it < ktN - 1) commit(kt + 1);
  }

  // ---- epilogue ----
  #pragma unroll
  for (int h = 0; h < NH; ++h) {
    float lf = l_[h];
    lf += __shfl_xor(lf, 16);
    lf += __shfl_xor(lf, 32);
    float linv = 1.0f / lf;
    if constexpr (SPLIT) {
      if (g == 0) {
        Ml[(size_t)split * NHEADS * SEQ + (size_t)bh * SEQ + qbase + h * 16 + l16] =
            float2{-negM[h], lf};
      }
      _Float16* op = Opart + (size_t)split * tensElems + (size_t)bh * headElems;
      #pragma unroll
      for (int ri = 0; ri < 4; ++ri) {
        float lB = __shfl(linv, 4 * g + ri);
        const int row = qbase + h * 16 + 4 * g + ri;
        #pragma unroll
        for (int nt = 0; nt < 4; ++nt)
          op[(size_t)row * HDIM + nt * 16 + l16] = (_Float16)(acc[h][nt][ri] * lB);
      }
    } else {
      #pragma unroll
      for (int ri = 0; ri < 4; ++ri) {
        float lB = __shfl(linv, 4 * g + ri);
        const int row = qbase + h * 16 + 4 * g + ri;
        #pragma unroll
        for (int nt = 0; nt < 4; ++nt)
          O[(size_t)row * HDIM + nt * 16 + l16] = acc[h][nt][ri] * lB;
      }
    }
  }
}

extern "C" void kernel_launch(void* const* d_in, const int* in_sizes, int n_in,
                              void* d_out, int out_size, void* d_ws, size_t ws_size,
                              hipStream_t stream) {
  const float* QKV = (const float*)d_in[0];
  float* Out = (float*)d_out;
  const size_t tensElems = (size_t)NHEADS * SEQ * HDIM;             // 4,194,304
  const size_t k16Bytes = tensElems * sizeof(_Float16);             // 8.39 MB
  const size_t vtBytes = tensElems * sizeof(short);                 // 8.39 MB
  const size_t opBytes = (size_t)NSPLIT * tensElems * sizeof(_Float16);  // 16.78 MB
  const size_t mlBytes = (size_t)NSPLIT * NHEADS * SEQ * 8;         // 1.05 MB

  dim3 block(256);

  if (ws_size >= k16Bytes + vtBytes + opBytes + mlBytes) {
    _Float16* K16 = (_Float16*)d_ws;
    short* Vt16 = (short*)((char*)d_ws + k16Bytes);
    _Float16* Opart = (_Float16*)((char*)d_ws + k16Bytes + vtBytes);
    float2* Ml = (float2*)((char*)d_ws + k16Bytes + vtBytes + opBytes);
    hipLaunchKernelGGL(prep, dim3(3072), block, 0, stream, QKV, K16, Vt16);
    hipLaunchKernelGGL((flash_attn<true, true>), dim3(NHEADS * (SEQ / BR), NSPLIT),
                       block, 0, stream, QKV, K16, Vt16, Out, Opart, Ml);
    hipLaunchKernelGGL(combine2, dim3((NHEADS * SEQ * HDIM / 8) / 256), block, 0,
                       stream, Opart, Ml, Out);
  } else {
    hipLaunchKernelGGL((flash_attn<false, false>), dim3(NHEADS * (SEQ / BR)), block,
                       0, stream, QKV, (const _Float16*)nullptr,
                       (const short*)nullptr, Out, (_Float16*)nullptr,
                       (float2*)nullptr);
  }
}